// Round 2
// baseline (2849.860 us; speedup 1.0000x reference)
//
#include <hip/hip_runtime.h>
#include <hip/hip_bf16.h>

// Model dims (fixed by the reference)
#define BB 16
#define LL 256
#define DD 768
#define HH 12
#define HDD 64
#define NLL 4
#define FF 3072
#define EE 50

typedef unsigned short ushort_t;
typedef __bf16 bf16x8 __attribute__((ext_vector_type(8)));
typedef float f32x4 __attribute__((ext_vector_type(4)));

__device__ __forceinline__ float b2f(ushort_t u) {
    union { unsigned int i; float f; } x; x.i = ((unsigned int)u) << 16; return x.f;
}
__device__ __forceinline__ ushort_t f2b(float f) {
    unsigned int u = __builtin_bit_cast(unsigned int, f);
    unsigned int r = u + 0x7fffu + ((u >> 16) & 1u);   // RNE
    return (ushort_t)(r >> 16);
}

__device__ __forceinline__ void gl2lds16(const void* g, void* l) {
    // async global->LDS, 16B per lane; LDS dst = wave-uniform base + lane*16
    __builtin_amdgcn_global_load_lds(
        (const __attribute__((address_space(1))) unsigned int*)g,
        (__attribute__((address_space(3))) unsigned int*)l,
        16, 0, 0);
}

// ---------------- fused transpose + fp32->bf16: out[C,R] = bf16(in[R,C]^T) ----------------
__global__ __launch_bounds__(256) void transpose_f2b(
    const float* __restrict__ in, ushort_t* __restrict__ out, int R, int C)
{
    __shared__ ushort_t tile[32][33];
    int c0 = blockIdx.x * 32, r0 = blockIdx.y * 32;
    int tx = threadIdx.x, ty = threadIdx.y; // (32,8)
#pragma unroll
    for (int i = 0; i < 32; i += 8)
        tile[ty + i][tx] = f2b(in[(long)(r0 + ty + i) * C + c0 + tx]);
    __syncthreads();
#pragma unroll
    for (int i = 0; i < 32; i += 8)
        out[(long)(c0 + ty + i) * R + r0 + tx] = tile[tx][ty + i];
}

// ---------------- embedding + sinusoidal pos ----------------
__global__ __launch_bounds__(256) void embed_kernel(
    const int* __restrict__ wids, const float* __restrict__ wemb,
    float* __restrict__ hf, ushort_t* __restrict__ hb)
{
    long idx = (long)blockIdx.x * 256 + threadIdx.x; // < 4096*768
    int d = (int)(idx % DD);
    int t = (int)(idx / DD);
    int lpos = t & (LL - 1);
    int wid = wids[t];
    float freq = expf(-9.210340371976184f * (float)(d & ~1) * (1.f / (float)DD));
    float ang = (float)lpos * freq;
    float pe = (d & 1) ? cosf(ang) : sinf(ang);
    float hv = wemb[(long)wid * DD + d] + pe;
    hf[idx] = hv;
    hb[idx] = f2b(hv);
}

// ---------------- bf16 MFMA GEMM: C[M,N] = A[M,K] @ Bt[N,K]^T + bias ----------------
// 128x128 tile, BK=32, 256 threads (4 waves, 2x2 wave grid, each wave 64x64)
__global__ __launch_bounds__(256) void gemm_bf16(
    const ushort_t* __restrict__ A, const ushort_t* __restrict__ Bt,
    const float* __restrict__ bias,
    ushort_t* __restrict__ outb, float* __restrict__ outf,
    int M, int N, int K, int relu)
{
    __shared__ __align__(16) ushort_t As[128 * 32];
    __shared__ __align__(16) ushort_t Bs[128 * 32];
    const int tid = threadIdx.x;
    const int wave = tid >> 6, lane = tid & 63;
    const int quad = lane >> 4, l16 = lane & 15;
    const int m0 = blockIdx.y * 128, n0 = blockIdx.x * 128;
    const int wm = (wave >> 1) * 64, wn = (wave & 1) * 64;
    const ushort_t* Ab = A + (long)m0 * K;
    const ushort_t* Bb = Bt + (long)n0 * K;

    f32x4 acc[4][4];
#pragma unroll
    for (int mi = 0; mi < 4; ++mi)
#pragma unroll
        for (int ni = 0; ni < 4; ++ni) acc[mi][ni] = (f32x4){0.f, 0.f, 0.f, 0.f};

    const int nk = K >> 5;
    for (int kt = 0; kt < nk; ++kt) {
        const int k0 = kt << 5;
        __syncthreads();  // previous tile's LDS reads done
#pragma unroll
        for (int i = 0; i < 2; ++i) {
            int c = tid + i * 256;         // chunk id; 512 chunks of 8 bf16
            int row = c >> 2, kc = (c & 3) * 8;
            char* la = (char*)As + (wave * 1024 + i * 4096); // wave-uniform base
            char* lb = (char*)Bs + (wave * 1024 + i * 4096);
            gl2lds16(&Ab[(long)row * K + k0 + kc], la);
            gl2lds16(&Bb[(long)row * K + k0 + kc], lb);
        }
        __syncthreads();  // barrier drains vmcnt
        bf16x8 af[4], bfr[4];
#pragma unroll
        for (int t = 0; t < 4; ++t)
            af[t] = *(const bf16x8*)&As[(wm + t * 16 + l16) * 32 + quad * 8];
#pragma unroll
        for (int t = 0; t < 4; ++t)
            bfr[t] = *(const bf16x8*)&Bs[(wn + t * 16 + l16) * 32 + quad * 8];
#pragma unroll
        for (int mi = 0; mi < 4; ++mi)
#pragma unroll
            for (int ni = 0; ni < 4; ++ni)
                acc[mi][ni] = __builtin_amdgcn_mfma_f32_16x16x32_bf16(
                    af[mi], bfr[ni], acc[mi][ni], 0, 0, 0);
    }

    // epilogue: C/D layout col=lane&15, row=quad*4+reg
#pragma unroll
    for (int ni = 0; ni < 4; ++ni) {
        int col = n0 + wn + ni * 16 + l16;
        float bv = bias ? bias[col] : 0.f;
#pragma unroll
        for (int mi = 0; mi < 4; ++mi) {
#pragma unroll
            for (int r = 0; r < 4; ++r) {
                int row = m0 + wm + mi * 16 + quad * 4 + r;
                float vv = acc[mi][ni][r] + bv;
                if (relu) vv = fmaxf(vv, 0.f);
                if (outb) outb[(long)row * N + col] = f2b(vv);
                if (outf) outf[(long)row * N + col] = vv;
            }
        }
    }
}

// ---------------- attention: one block per (b,h), one thread per query row ----------------
__global__ __launch_bounds__(256) void attn_kernel(
    const ushort_t* __restrict__ q, const ushort_t* __restrict__ k,
    const ushort_t* __restrict__ v,
    const int* __restrict__ adjm, const int* __restrict__ etyp,
    const float* __restrict__ eemb, ushort_t* __restrict__ out)
{
    __shared__ __align__(16) ushort_t Ks[128 * 64];
    __shared__ __align__(16) ushort_t Vs[128 * 64];
    __shared__ float Es[EE * 67]; // stride 67 (odd mod 32) spreads random-gather banks
    const int blk = blockIdx.x;
    const int b = blk / HH, h = blk % HH;
    const int tid = threadIdx.x;  // = query row i

    // stage edge-embedding table (50x64 fp32, padded stride 67)
    for (int c = tid; c < EE * 64; c += 256)
        Es[(c >> 6) * 67 + (c & 63)] = eemb[c];

    // per-thread q row (fp32)
    float qf[HDD];
    const ushort_t* qrow = q + ((long)(b * LL + tid)) * DD + h * HDD;
#pragma unroll
    for (int d = 0; d < HDD; ++d) qf[d] = b2f(qrow[d]);

    float m = -1e30f, l = 0.f;
    float acc[HDD];
#pragma unroll
    for (int d = 0; d < HDD; ++d) acc[d] = 0.f;

    const int* adjrow = adjm + ((long)b * LL + tid) * LL;
    const int* etrow  = etyp + ((long)b * LL + tid) * LL;

    for (int ch = 0; ch < 2; ++ch) {
        __syncthreads();
        const ushort_t* kb = k + ((long)(b * LL + ch * 128)) * DD + h * HDD;
        const ushort_t* vb = v + ((long)(b * LL + ch * 128)) * DD + h * HDD;
        for (int c = tid; c < 1024; c += 256) {  // 128*64/8 chunks
            int j = c >> 3, dc = (c & 7) * 8;
            *(int4*)&Ks[j * 64 + dc] = *(const int4*)&kb[(long)j * DD + dc];
            *(int4*)&Vs[j * 64 + dc] = *(const int4*)&vb[(long)j * DD + dc];
        }
        __syncthreads();
        for (int jj = 0; jj < 128; ++jj) {
            int j = ch * 128 + jj;
            int et = etrow[j];
            const ushort_t* kr = &Ks[jj * 64];
            const float* er = &Es[et * 67];
            float s = 0.f, s2 = 0.f;
#pragma unroll
            for (int d = 0; d < HDD; ++d) {
                s  = fmaf(qf[d], b2f(kr[d]), s);
                s2 = fmaf(qf[d], er[d], s2);
            }
            float sc = adjrow[j] ? (s + s2) * 0.125f : -1e9f;
            float mn = fmaxf(m, sc);
            float corr = __expf(m - mn);
            float p = __expf(sc - mn);
            l = l * corr + p;
            const ushort_t* vr = &Vs[jj * 64];
#pragma unroll
            for (int d = 0; d < HDD; ++d) acc[d] = fmaf(p, b2f(vr[d]), acc[d] * corr);
            m = mn;
        }
    }
    float inv = 1.f / l;
    ushort_t* ob = out + ((long)(b * LL + tid)) * DD + h * HDD;
#pragma unroll
    for (int d = 0; d < HDD; ++d) ob[d] = f2b(acc[d] * inv);
}

// ---------------- residual + layernorm (row = 768, block = 256) ----------------
__global__ __launch_bounds__(256) void ln_kernel(
    float* __restrict__ hf, ushort_t* __restrict__ hb,
    const float* __restrict__ proj,
    const float* __restrict__ g, const float* __restrict__ be)
{
    const int r = blockIdx.x, tid = threadIdx.x;
    const long rb = (long)r * DD;
    float x[3];
#pragma unroll
    for (int i = 0; i < 3; ++i) { int d = tid + i * 256; x[i] = hf[rb + d] + proj[rb + d]; }
    float s = x[0] + x[1] + x[2];
    float s2 = x[0] * x[0] + x[1] * x[1] + x[2] * x[2];
#pragma unroll
    for (int o = 1; o < 64; o <<= 1) { s += __shfl_xor(s, o); s2 += __shfl_xor(s2, o); }
    __shared__ float rs[4], rq[4];
    int wave = tid >> 6;
    if ((tid & 63) == 0) { rs[wave] = s; rq[wave] = s2; }
    __syncthreads();
    float S  = rs[0] + rs[1] + rs[2] + rs[3];
    float S2 = rq[0] + rq[1] + rq[2] + rq[3];
    float mean = S * (1.f / (float)DD);
    float var  = S2 * (1.f / (float)DD) - mean * mean;
    float rstd = rsqrtf(var + 1e-5f);
#pragma unroll
    for (int i = 0; i < 3; ++i) {
        int d = tid + i * 256;
        float y = (x[i] - mean) * rstd * g[d] + be[d];
        hf[rb + d] = y;
        hb[rb + d] = f2b(y);
    }
}

// ---------------- classifier head ----------------
__global__ __launch_bounds__(256) void cls_kernel(
    const float* __restrict__ hf, const float* __restrict__ W,
    const float* __restrict__ bias, float* __restrict__ out)
{
    int b = blockIdx.x, tid = threadIdx.x;
    const float* hr = hf + (long)b * LL * DD; // row b*L + 0
    float p0 = 0.f, p1 = 0.f;
    for (int d = tid; d < DD; d += 256) {
        float hv = hr[d];
        p0 = fmaf(hv, W[d * 2 + 0], p0);
        p1 = fmaf(hv, W[d * 2 + 1], p1);
    }
#pragma unroll
    for (int o = 1; o < 64; o <<= 1) { p0 += __shfl_xor(p0, o); p1 += __shfl_xor(p1, o); }
    __shared__ float r0[4], r1[4];
    int wave = tid >> 6;
    if ((tid & 63) == 0) { r0[wave] = p0; r1[wave] = p1; }
    __syncthreads();
    if (tid == 0) {
        out[b * 2 + 0] = r0[0] + r0[1] + r0[2] + r0[3] + bias[0];
        out[b * 2 + 1] = r1[0] + r1[1] + r1[2] + r1[3] + bias[1];
    }
}

extern "C" void kernel_launch(void* const* d_in, const int* in_sizes, int n_in,
                              void* d_out, int out_size, void* d_ws, size_t ws_size,
                              hipStream_t stream)
{
    const int* word_ids = (const int*)d_in[0];
    const int* adjm     = (const int*)d_in[1];   // bool in ref; assuming int32 delivery
    const int* etyp     = (const int*)d_in[2];
    const float* wemb   = (const float*)d_in[3];
    const float* eemb   = (const float*)d_in[4];
    const float* Wq     = (const float*)d_in[5];
    const float* bq     = (const float*)d_in[6];
    const float* Wk     = (const float*)d_in[7];
    const float* bk     = (const float*)d_in[8];
    const float* Wv     = (const float*)d_in[9];
    const float* bv     = (const float*)d_in[10];
    const float* Wo     = (const float*)d_in[11];
    const float* bo     = (const float*)d_in[12];
    const float* ln1g   = (const float*)d_in[13];
    const float* ln1b   = (const float*)d_in[14];
    const float* W1     = (const float*)d_in[15];
    const float* b1     = (const float*)d_in[16];
    const float* W2     = (const float*)d_in[17];
    const float* b2     = (const float*)d_in[18];
    const float* ln2g   = (const float*)d_in[19];
    const float* ln2b   = (const float*)d_in[20];
    const float* clsW   = (const float*)d_in[21];
    const float* clsb   = (const float*)d_in[22];
    float* outp = (float*)d_out;

    char* ws = (char*)d_ws;
    size_t off = 0;
    auto alloc = [&](size_t bytes) -> char* {
        char* p = ws + off;
        off += (bytes + 255) & ~(size_t)255;
        return p;
    };
    const size_t DxD = (size_t)DD * DD;      // 589824
    const size_t DxF = (size_t)DD * FF;      // 2359296
    const size_t TOK = (size_t)BB * LL;      // 4096

    float*    hf  = (float*)alloc(TOK * DD * 4);      // 12.58 MB fp32 residual
    ushort_t* hb  = (ushort_t*)alloc(TOK * DD * 2);   // 6.29 MB
    ushort_t* tw  = (ushort_t*)alloc(DxF * 2);        // 4.72 MB transposed-weight slot
    ushort_t* qb  = (ushort_t*)alloc(TOK * DD * 2);   // q
    ushort_t* kb2 = (ushort_t*)alloc(TOK * DD * 2);   // k
    ushort_t* vb2 = (ushort_t*)alloc(TOK * DD * 2);   // v
    ushort_t* ao  = (ushort_t*)alloc(TOK * DD * 2);   // attn out
    float*    pjf = (float*)alloc(TOK * DD * 4);      // projection (fp32)
    ushort_t* ff1 = qb;  // aliases q/k/v/ao region (exactly 25.17 MB), dead by FFN time
    (void)ws_size; (void)in_sizes; (void)n_in; (void)out_size;
    // total ws: ~58.5 MiB

    embed_kernel<<<(int)(TOK * DD / 256), 256, 0, stream>>>(word_ids, wemb, hf, hb);

    dim3 tb(32, 8, 1);
    const int M = (int)TOK; // 4096
    for (int l = 0; l < NLL; ++l) {
        // Q = hb @ Wq + bq
        transpose_f2b<<<dim3(24, 24), tb, 0, stream>>>(Wq + (size_t)l * DxD, tw, DD, DD);
        gemm_bf16<<<dim3(DD / 128, M / 128), 256, 0, stream>>>(
            hb, tw, bq + l * DD, qb, nullptr, M, DD, DD, 0);
        // K
        transpose_f2b<<<dim3(24, 24), tb, 0, stream>>>(Wk + (size_t)l * DxD, tw, DD, DD);
        gemm_bf16<<<dim3(DD / 128, M / 128), 256, 0, stream>>>(
            hb, tw, bk + l * DD, kb2, nullptr, M, DD, DD, 0);
        // V
        transpose_f2b<<<dim3(24, 24), tb, 0, stream>>>(Wv + (size_t)l * DxD, tw, DD, DD);
        gemm_bf16<<<dim3(DD / 128, M / 128), 256, 0, stream>>>(
            hb, tw, bv + l * DD, vb2, nullptr, M, DD, DD, 0);
        // attention
        attn_kernel<<<BB * HH, 256, 0, stream>>>(qb, kb2, vb2, adjm, etyp, eemb, ao);
        // O-proj (fp32 out)
        transpose_f2b<<<dim3(24, 24), tb, 0, stream>>>(Wo + (size_t)l * DxD, tw, DD, DD);
        gemm_bf16<<<dim3(DD / 128, M / 128), 256, 0, stream>>>(
            ao, tw, bo + l * DD, nullptr, pjf, M, DD, DD, 0);
        ln_kernel<<<M, 256, 0, stream>>>(hf, hb, pjf, ln1g + l * DD, ln1b + l * DD);
        // FFN1 (relu) — note ff1 aliases q/k/v/ao which are now dead
        transpose_f2b<<<dim3(96, 24), tb, 0, stream>>>(W1 + (size_t)l * DxF, tw, DD, FF);
        gemm_bf16<<<dim3(FF / 128, M / 128), 256, 0, stream>>>(
            hb, tw, b1 + l * FF, ff1, nullptr, M, FF, DD, 1);
        // FFN2 (fp32 out)
        transpose_f2b<<<dim3(24, 96), tb, 0, stream>>>(W2 + (size_t)l * DxF, tw, FF, DD);
        gemm_bf16<<<dim3(DD / 128, M / 128), 256, 0, stream>>>(
            ff1, tw, b2 + l * DD, nullptr, pjf, M, DD, FF, 0);
        ln_kernel<<<M, 256, 0, stream>>>(hf, hb, pjf, ln2g + l * DD, ln2b + l * DD);
    }
    cls_kernel<<<BB, 256, 0, stream>>>(hf, clsW, clsb, outp);
}

// Round 3
// 1390.454 us; speedup vs baseline: 2.0496x; 2.0496x over previous
//
#include <hip/hip_runtime.h>
#include <hip/hip_bf16.h>

// Model dims (fixed by the reference)
#define BB 16
#define LL 256
#define DD 768
#define HH 12
#define HDD 64
#define NLL 4
#define FF 3072
#define EE 50

typedef unsigned short ushort_t;
typedef __bf16 bf16x8 __attribute__((ext_vector_type(8)));
typedef float f32x4 __attribute__((ext_vector_type(4)));

__device__ __forceinline__ float b2f(ushort_t u) {
    union { unsigned int i; float f; } x; x.i = ((unsigned int)u) << 16; return x.f;
}
__device__ __forceinline__ ushort_t f2b(float f) {
    unsigned int u = __builtin_bit_cast(unsigned int, f);
    unsigned int r = u + 0x7fffu + ((u >> 16) & 1u);   // RNE
    return (ushort_t)(r >> 16);
}

__device__ __forceinline__ void gl2lds16(const void* g, void* l) {
    __builtin_amdgcn_global_load_lds(
        (const __attribute__((address_space(1))) unsigned int*)g,
        (__attribute__((address_space(3))) unsigned int*)l,
        16, 0, 0);
}

// ---------------- fused transpose + fp32->bf16: out[C,R] = bf16(in[R,C]^T) ----------------
__global__ __launch_bounds__(256) void transpose_f2b(
    const float* __restrict__ in, ushort_t* __restrict__ out, int R, int C)
{
    __shared__ ushort_t tile[32][33];
    int c0 = blockIdx.x * 32, r0 = blockIdx.y * 32;
    int tx = threadIdx.x, ty = threadIdx.y; // (32,8)
#pragma unroll
    for (int i = 0; i < 32; i += 8)
        tile[ty + i][tx] = f2b(in[(long)(r0 + ty + i) * C + c0 + tx]);
    __syncthreads();
#pragma unroll
    for (int i = 0; i < 32; i += 8)
        out[(long)(c0 + ty + i) * R + r0 + tx] = tile[tx][ty + i];
}

// ---------------- embedding + sinusoidal pos ----------------
__global__ __launch_bounds__(256) void embed_kernel(
    const int* __restrict__ wids, const float* __restrict__ wemb,
    float* __restrict__ hf, ushort_t* __restrict__ hb)
{
    long idx = (long)blockIdx.x * 256 + threadIdx.x; // < 4096*768
    int d = (int)(idx % DD);
    int t = (int)(idx / DD);
    int lpos = t & (LL - 1);
    int wid = wids[t];
    float freq = expf(-9.210340371976184f * (float)(d & ~1) * (1.f / (float)DD));
    float ang = (float)lpos * freq;
    float pe = (d & 1) ? cosf(ang) : sinf(ang);
    float hv = wemb[(long)wid * DD + d] + pe;
    hf[idx] = hv;
    hb[idx] = f2b(hv);
}

// ---------------- bf16 MFMA GEMM: C[M,N] = A[M,K] @ Bt[N,K]^T + bias ----------------
__global__ __launch_bounds__(256) void gemm_bf16(
    const ushort_t* __restrict__ A, const ushort_t* __restrict__ Bt,
    const float* __restrict__ bias,
    ushort_t* __restrict__ outb, float* __restrict__ outf,
    int M, int N, int K, int relu)
{
    __shared__ __align__(16) ushort_t As[128 * 32];
    __shared__ __align__(16) ushort_t Bs[128 * 32];
    const int tid = threadIdx.x;
    const int wave = tid >> 6, lane = tid & 63;
    const int quad = lane >> 4, l16 = lane & 15;
    const int m0 = blockIdx.y * 128, n0 = blockIdx.x * 128;
    const int wm = (wave >> 1) * 64, wn = (wave & 1) * 64;
    const ushort_t* Ab = A + (long)m0 * K;
    const ushort_t* Bb = Bt + (long)n0 * K;

    f32x4 acc[4][4];
#pragma unroll
    for (int mi = 0; mi < 4; ++mi)
#pragma unroll
        for (int ni = 0; ni < 4; ++ni) acc[mi][ni] = (f32x4){0.f, 0.f, 0.f, 0.f};

    const int nk = K >> 5;
    for (int kt = 0; kt < nk; ++kt) {
        const int k0 = kt << 5;
        __syncthreads();
#pragma unroll
        for (int i = 0; i < 2; ++i) {
            int c = tid + i * 256;
            int row = c >> 2, kc = (c & 3) * 8;
            char* la = (char*)As + (wave * 1024 + i * 4096);
            char* lb = (char*)Bs + (wave * 1024 + i * 4096);
            gl2lds16(&Ab[(long)row * K + k0 + kc], la);
            gl2lds16(&Bb[(long)row * K + k0 + kc], lb);
        }
        __syncthreads();
        bf16x8 af[4], bfr[4];
#pragma unroll
        for (int t = 0; t < 4; ++t)
            af[t] = *(const bf16x8*)&As[(wm + t * 16 + l16) * 32 + quad * 8];
#pragma unroll
        for (int t = 0; t < 4; ++t)
            bfr[t] = *(const bf16x8*)&Bs[(wn + t * 16 + l16) * 32 + quad * 8];
#pragma unroll
        for (int mi = 0; mi < 4; ++mi)
#pragma unroll
            for (int ni = 0; ni < 4; ++ni)
                acc[mi][ni] = __builtin_amdgcn_mfma_f32_16x16x32_bf16(
                    af[mi], bfr[ni], acc[mi][ni], 0, 0, 0);
    }

#pragma unroll
    for (int ni = 0; ni < 4; ++ni) {
        int col = n0 + wn + ni * 16 + l16;
        float bv = bias ? bias[col] : 0.f;
#pragma unroll
        for (int mi = 0; mi < 4; ++mi) {
#pragma unroll
            for (int r = 0; r < 4; ++r) {
                int row = m0 + wm + mi * 16 + quad * 4 + r;
                float vv = acc[mi][ni][r] + bv;
                if (relu) vv = fmaxf(vv, 0.f);
                if (outb) outb[(long)row * N + col] = f2b(vv);
                if (outf) outf[(long)row * N + col] = vv;
            }
        }
    }
}

// ---------------- MFMA attention ----------------
// Block = (b, h, 16-query tile). 256 threads = 4 waves.
// Phase 1: Pe[q][e] = q . eemb_e  (MFMA, wave w does e-tile w)
// Phase 2: S[q][j] = q . k_j      (MFMA, wave w does keys w*64..w*64+63; K B-frags from global)
// Phase 3: softmax with fused mask + edge gather Pe[q][et[q][j]]; P bf16 unnormalized
// Phase 4: O = P @ V via MFMA (V^T staged in LDS), normalize by 1/rowsum in epilogue
#define QS_STR 72
#define VT_STR 264
#define P_STR  264
#define S_STR  257
#define PE_STR 53

__global__ __launch_bounds__(256) void attn_kernel(
    const ushort_t* __restrict__ q, const ushort_t* __restrict__ k,
    const ushort_t* __restrict__ v,
    const int* __restrict__ adjm, const int* __restrict__ etyp,
    const float* __restrict__ eemb, ushort_t* __restrict__ out)
{
    __shared__ __align__(16) char smem[64448];
    ushort_t* VT = (ushort_t*)smem;                         // 64 x 264 bf16 = 33792 B
    float*    S  = (float*)(smem + 33792);                  // 16 x 257 f32  = 16448 B
    ushort_t* P  = (ushort_t*)(smem + 50240);               // 16 x 264 bf16 =  8448 B
    float*    Pe = (float*)(smem + 58688);                  // 16 x 53 f32   =  3392 B
    char*     U  = smem + 62080;                            // union: Qs / red (2304 B)
    float* invrow = (float*)(smem + 64384);                 // 16 f32
    ushort_t* Qs = (ushort_t*)U;                            // 16 x 72 bf16
    float*    red = (float*)U;                              // [2][16][17]

    const int blk = blockIdx.x;
    const int qt = blk & 15;
    const int h  = (blk >> 4) % HH;
    const int b  = blk / (16 * HH);
    const int i0 = qt * 16;
    const int tid = threadIdx.x;
    const int wave = tid >> 6, lane = tid & 63;
    const int quad = lane >> 4, l16 = lane & 15;

    // ---- stage Qs (16x64) and VT (64x256, transposed) ----
    if (tid < 128) {
        int row = tid >> 3, d0 = (tid & 7) * 8;
        *(int4*)&Qs[row * QS_STR + d0] =
            *(const int4*)&q[((long)(b * LL + i0 + row)) * DD + h * HDD + d0];
    }
#pragma unroll
    for (int i = 0; i < 8; ++i) {
        int c = tid + i * 256;           // 2048 chunks
        int j = c >> 3, d0 = (c & 7) * 8;
        int4 raw = *(const int4*)&v[((long)(b * LL + j)) * DD + h * HDD + d0];
        const ushort_t* vals = (const ushort_t*)&raw;
#pragma unroll
        for (int u = 0; u < 8; ++u) VT[(d0 + u) * VT_STR + j] = vals[u];
    }
    __syncthreads();

    // ---- phase 1: Pe = Q @ E^T  (wave w handles e-tile w: e = w*16 + l16) ----
    {
        int e = wave * 16 + l16;
        f32x4 acc = (f32x4){0.f, 0.f, 0.f, 0.f};
#pragma unroll
        for (int kk = 0; kk < 2; ++kk) {
            bf16x8 af = *(const bf16x8*)&Qs[l16 * QS_STR + kk * 32 + quad * 8];
            bf16x8 bf = (bf16x8){0, 0, 0, 0, 0, 0, 0, 0};
            if (e < EE) {
                const float* ep = &eemb[(long)e * HDD + kk * 32 + quad * 8];
#pragma unroll
                for (int u = 0; u < 8; ++u) bf[u] = (__bf16)ep[u];
            }
            acc = __builtin_amdgcn_mfma_f32_16x16x32_bf16(af, bf, acc, 0, 0, 0);
        }
        if (e < EE) {
#pragma unroll
            for (int r = 0; r < 4; ++r) Pe[(quad * 4 + r) * PE_STR + e] = acc[r];
        }
    }

    // ---- phase 2: S = Q @ K^T  (wave w: keys w*64 .. w*64+63) ----
#pragma unroll
    for (int jt = 0; jt < 4; ++jt) {
        int jtile = wave * 4 + jt;
        int j = jtile * 16 + l16;
        f32x4 acc = (f32x4){0.f, 0.f, 0.f, 0.f};
#pragma unroll
        for (int kk = 0; kk < 2; ++kk) {
            bf16x8 af = *(const bf16x8*)&Qs[l16 * QS_STR + kk * 32 + quad * 8];
            bf16x8 bf = *(const bf16x8*)&k[((long)(b * LL + j)) * DD + h * HDD + kk * 32 + quad * 8];
            acc = __builtin_amdgcn_mfma_f32_16x16x32_bf16(af, bf, acc, 0, 0, 0);
        }
#pragma unroll
        for (int r = 0; r < 4; ++r)
            S[(quad * 4 + r) * S_STR + jtile * 16 + l16] = acc[r];
    }
    __syncthreads();

    // ---- phase 3: masked softmax with edge term; P = exp(s - max) in bf16 ----
    {
        const int row = tid & 15, seg = tid >> 4;      // 16 cols per thread
        const int i = i0 + row;
        const int* etp = etyp + ((long)(b * LL + i)) * LL + seg * 16;
        const int* adp = adjm + ((long)(b * LL + i)) * LL + seg * 16;
        int etv[16], adv[16];
#pragma unroll
        for (int t = 0; t < 4; ++t) {
            *(int4*)&etv[t * 4] = *(const int4*)&etp[t * 4];
            *(int4*)&adv[t * 4] = *(const int4*)&adp[t * 4];
        }
        float vals[16];
        float pmax = -1e30f;
#pragma unroll
        for (int c = 0; c < 16; ++c) {
            float s = S[row * S_STR + seg * 16 + c];
            float pe = Pe[row * PE_STR + etv[c]];
            float vv = adv[c] ? (s + pe) * 0.125f : -1e30f;
            vals[c] = vv;
            pmax = fmaxf(pmax, vv);
        }
        red[row * 17 + seg] = pmax;
        __syncthreads();
        float m = -1e30f;
#pragma unroll
        for (int g = 0; g < 16; ++g) m = fmaxf(m, red[row * 17 + g]);
        float sum = 0.f;
#pragma unroll
        for (int c = 0; c < 16; ++c) {
            float p = __expf(vals[c] - m);
            ushort_t pb = f2b(p);
            sum += b2f(pb);
            P[row * P_STR + seg * 16 + c] = pb;
        }
        red[272 + row * 17 + seg] = sum;
        __syncthreads();
        if (tid < 16) {
            float tot = 0.f;
#pragma unroll
            for (int g = 0; g < 16; ++g) tot += red[272 + tid * 17 + g];
            invrow[tid] = 1.f / tot;
        }
        __syncthreads();
    }

    // ---- phase 4: O = P @ V  (wave w: d-tile w) ----
    {
        f32x4 acc = (f32x4){0.f, 0.f, 0.f, 0.f};
#pragma unroll
        for (int kt = 0; kt < 8; ++kt) {
            bf16x8 af = *(const bf16x8*)&P[l16 * P_STR + kt * 32 + quad * 8];
            bf16x8 bf = *(const bf16x8*)&VT[(wave * 16 + l16) * VT_STR + kt * 32 + quad * 8];
            acc = __builtin_amdgcn_mfma_f32_16x16x32_bf16(af, bf, acc, 0, 0, 0);
        }
#pragma unroll
        for (int r = 0; r < 4; ++r) {
            int row = quad * 4 + r;
            float ov = acc[r] * invrow[row];
            out[((long)(b * LL + i0 + row)) * DD + h * HDD + wave * 16 + l16] = f2b(ov);
        }
    }
}

// ---------------- residual + layernorm (row = 768, block = 256) ----------------
__global__ __launch_bounds__(256) void ln_kernel(
    float* __restrict__ hf, ushort_t* __restrict__ hb,
    const float* __restrict__ proj,
    const float* __restrict__ g, const float* __restrict__ be)
{
    const int r = blockIdx.x, tid = threadIdx.x;
    const long rb = (long)r * DD;
    float x[3];
#pragma unroll
    for (int i = 0; i < 3; ++i) { int d = tid + i * 256; x[i] = hf[rb + d] + proj[rb + d]; }
    float s = x[0] + x[1] + x[2];
    float s2 = x[0] * x[0] + x[1] * x[1] + x[2] * x[2];
#pragma unroll
    for (int o = 1; o < 64; o <<= 1) { s += __shfl_xor(s, o); s2 += __shfl_xor(s2, o); }
    __shared__ float rs[4], rq[4];
    int wave = tid >> 6;
    if ((tid & 63) == 0) { rs[wave] = s; rq[wave] = s2; }
    __syncthreads();
    float S  = rs[0] + rs[1] + rs[2] + rs[3];
    float S2 = rq[0] + rq[1] + rq[2] + rq[3];
    float mean = S * (1.f / (float)DD);
    float var  = S2 * (1.f / (float)DD) - mean * mean;
    float rstd = rsqrtf(var + 1e-5f);
#pragma unroll
    for (int i = 0; i < 3; ++i) {
        int d = tid + i * 256;
        float y = (x[i] - mean) * rstd * g[d] + be[d];
        hf[rb + d] = y;
        hb[rb + d] = f2b(y);
    }
}

// ---------------- classifier head ----------------
__global__ __launch_bounds__(256) void cls_kernel(
    const float* __restrict__ hf, const float* __restrict__ W,
    const float* __restrict__ bias, float* __restrict__ out)
{
    int b = blockIdx.x, tid = threadIdx.x;
    const float* hr = hf + (long)b * LL * DD;
    float p0 = 0.f, p1 = 0.f;
    for (int d = tid; d < DD; d += 256) {
        float hv = hr[d];
        p0 = fmaf(hv, W[d * 2 + 0], p0);
        p1 = fmaf(hv, W[d * 2 + 1], p1);
    }
#pragma unroll
    for (int o = 1; o < 64; o <<= 1) { p0 += __shfl_xor(p0, o); p1 += __shfl_xor(p1, o); }
    __shared__ float r0[4], r1[4];
    int wave = tid >> 6;
    if ((tid & 63) == 0) { r0[wave] = p0; r1[wave] = p1; }
    __syncthreads();
    if (tid == 0) {
        out[b * 2 + 0] = r0[0] + r0[1] + r0[2] + r0[3] + bias[0];
        out[b * 2 + 1] = r1[0] + r1[1] + r1[2] + r1[3] + bias[1];
    }
}

extern "C" void kernel_launch(void* const* d_in, const int* in_sizes, int n_in,
                              void* d_out, int out_size, void* d_ws, size_t ws_size,
                              hipStream_t stream)
{
    const int* word_ids = (const int*)d_in[0];
    const int* adjm     = (const int*)d_in[1];
    const int* etyp     = (const int*)d_in[2];
    const float* wemb   = (const float*)d_in[3];
    const float* eemb   = (const float*)d_in[4];
    const float* Wq     = (const float*)d_in[5];
    const float* bq     = (const float*)d_in[6];
    const float* Wk     = (const float*)d_in[7];
    const float* bk     = (const float*)d_in[8];
    const float* Wv     = (const float*)d_in[9];
    const float* bv     = (const float*)d_in[10];
    const float* Wo     = (const float*)d_in[11];
    const float* bo     = (const float*)d_in[12];
    const float* ln1g   = (const float*)d_in[13];
    const float* ln1b   = (const float*)d_in[14];
    const float* W1     = (const float*)d_in[15];
    const float* b1     = (const float*)d_in[16];
    const float* W2     = (const float*)d_in[17];
    const float* b2     = (const float*)d_in[18];
    const float* ln2g   = (const float*)d_in[19];
    const float* ln2b   = (const float*)d_in[20];
    const float* clsW   = (const float*)d_in[21];
    const float* clsb   = (const float*)d_in[22];
    float* outp = (float*)d_out;

    char* ws = (char*)d_ws;
    size_t off = 0;
    auto alloc = [&](size_t bytes) -> char* {
        char* p = ws + off;
        off += (bytes + 255) & ~(size_t)255;
        return p;
    };
    const size_t DxD = (size_t)DD * DD;
    const size_t DxF = (size_t)DD * FF;
    const size_t TOK = (size_t)BB * LL;

    float*    hf  = (float*)alloc(TOK * DD * 4);
    ushort_t* hb  = (ushort_t*)alloc(TOK * DD * 2);
    ushort_t* tw  = (ushort_t*)alloc(DxF * 2);
    ushort_t* qb  = (ushort_t*)alloc(TOK * DD * 2);
    ushort_t* kb2 = (ushort_t*)alloc(TOK * DD * 2);
    ushort_t* vb2 = (ushort_t*)alloc(TOK * DD * 2);
    ushort_t* ao  = (ushort_t*)alloc(TOK * DD * 2);
    float*    pjf = (float*)alloc(TOK * DD * 4);
    ushort_t* ff1 = qb;  // aliases q/k/v/ao region, dead by FFN time
    (void)ws_size; (void)in_sizes; (void)n_in; (void)out_size;

    embed_kernel<<<(int)(TOK * DD / 256), 256, 0, stream>>>(word_ids, wemb, hf, hb);

    dim3 tb(32, 8, 1);
    const int M = (int)TOK; // 4096
    for (int l = 0; l < NLL; ++l) {
        transpose_f2b<<<dim3(24, 24), tb, 0, stream>>>(Wq + (size_t)l * DxD, tw, DD, DD);
        gemm_bf16<<<dim3(DD / 128, M / 128), 256, 0, stream>>>(
            hb, tw, bq + l * DD, qb, nullptr, M, DD, DD, 0);
        transpose_f2b<<<dim3(24, 24), tb, 0, stream>>>(Wk + (size_t)l * DxD, tw, DD, DD);
        gemm_bf16<<<dim3(DD / 128, M / 128), 256, 0, stream>>>(
            hb, tw, bk + l * DD, kb2, nullptr, M, DD, DD, 0);
        transpose_f2b<<<dim3(24, 24), tb, 0, stream>>>(Wv + (size_t)l * DxD, tw, DD, DD);
        gemm_bf16<<<dim3(DD / 128, M / 128), 256, 0, stream>>>(
            hb, tw, bv + l * DD, vb2, nullptr, M, DD, DD, 0);
        attn_kernel<<<BB * HH * 16, 256, 0, stream>>>(qb, kb2, vb2, adjm, etyp, eemb, ao);
        transpose_f2b<<<dim3(24, 24), tb, 0, stream>>>(Wo + (size_t)l * DxD, tw, DD, DD);
        gemm_bf16<<<dim3(DD / 128, M / 128), 256, 0, stream>>>(
            ao, tw, bo + l * DD, nullptr, pjf, M, DD, DD, 0);
        ln_kernel<<<M, 256, 0, stream>>>(hf, hb, pjf, ln1g + l * DD, ln1b + l * DD);
        transpose_f2b<<<dim3(96, 24), tb, 0, stream>>>(W1 + (size_t)l * DxF, tw, DD, FF);
        gemm_bf16<<<dim3(FF / 128, M / 128), 256, 0, stream>>>(
            hb, tw, b1 + l * FF, ff1, nullptr, M, FF, DD, 1);
        transpose_f2b<<<dim3(24, 96), tb, 0, stream>>>(W2 + (size_t)l * DxF, tw, FF, DD);
        gemm_bf16<<<dim3(DD / 128, M / 128), 256, 0, stream>>>(
            ff1, tw, b2 + l * DD, nullptr, pjf, M, DD, FF, 0);
        ln_kernel<<<M, 256, 0, stream>>>(hf, hb, pjf, ln2g + l * DD, ln2b + l * DD);
    }
    cls_kernel<<<BB, 256, 0, stream>>>(hf, clsW, clsb, outp);
}

// Round 4
// 1248.173 us; speedup vs baseline: 2.2832x; 1.1140x over previous
//
#include <hip/hip_runtime.h>
#include <hip/hip_bf16.h>

// Model dims (fixed by the reference)
#define BB 16
#define LL 256
#define DD 768
#define HH 12
#define HDD 64
#define NLL 4
#define FF 3072
#define EE 50
#define QKVS 2304            // fused q|k|v row stride
#define TOKD ((size_t)BB * LL * DD)   // 3,145,728

typedef unsigned short ushort_t;
typedef __bf16 bf16x8 __attribute__((ext_vector_type(8)));
typedef float f32x4 __attribute__((ext_vector_type(4)));

__device__ __forceinline__ float b2f(ushort_t u) {
    union { unsigned int i; float f; } x; x.i = ((unsigned int)u) << 16; return x.f;
}
__device__ __forceinline__ ushort_t f2b(float f) {
    unsigned int u = __builtin_bit_cast(unsigned int, f);
    unsigned int r = u + 0x7fffu + ((u >> 16) & 1u);   // RNE
    return (ushort_t)(r >> 16);
}

__device__ __forceinline__ void gl2lds16(const void* g, void* l) {
    __builtin_amdgcn_global_load_lds(
        (const __attribute__((address_space(1))) unsigned int*)g,
        (__attribute__((address_space(3))) unsigned int*)l,
        16, 0, 0);
}

// ---------------- fused transpose + fp32->bf16: out[C,R] = bf16(in[R,C]^T), batched over z ----------------
__global__ __launch_bounds__(256) void transpose_f2b(
    const float* __restrict__ in, ushort_t* __restrict__ out, int R, int C,
    long inZ, long outZ)
{
    __shared__ ushort_t tile[32][33];
    in  += (long)blockIdx.z * inZ;
    out += (long)blockIdx.z * outZ;
    int c0 = blockIdx.x * 32, r0 = blockIdx.y * 32;
    int tx = threadIdx.x, ty = threadIdx.y; // (32,8)
#pragma unroll
    for (int i = 0; i < 32; i += 8)
        tile[ty + i][tx] = f2b(in[(long)(r0 + ty + i) * C + c0 + tx]);
    __syncthreads();
#pragma unroll
    for (int i = 0; i < 32; i += 8)
        out[(long)(c0 + ty + i) * R + r0 + tx] = tile[tx][ty + i];
}

// ---------------- concat bq|bk|bv for layer l into float[2304] ----------------
__global__ __launch_bounds__(256) void fuse_bias_kernel(
    const float* __restrict__ bq, const float* __restrict__ bk,
    const float* __restrict__ bv, int l, float* __restrict__ out)
{
    int n = blockIdx.x * 256 + threadIdx.x;
    if (n >= QKVS) return;
    float v = (n < DD) ? bq[l * DD + n]
            : (n < 2 * DD) ? bk[l * DD + n - DD]
            : bv[l * DD + n - 2 * DD];
    out[n] = v;
}

// ---------------- embedding + sinusoidal pos ----------------
__global__ __launch_bounds__(256) void embed_kernel(
    const int* __restrict__ wids, const float* __restrict__ wemb,
    float* __restrict__ hf, ushort_t* __restrict__ hb)
{
    long idx = (long)blockIdx.x * 256 + threadIdx.x; // < 4096*768
    int d = (int)(idx % DD);
    int t = (int)(idx / DD);
    int lpos = t & (LL - 1);
    int wid = wids[t];
    float freq = expf(-9.210340371976184f * (float)(d & ~1) * (1.f / (float)DD));
    float ang = (float)lpos * freq;
    float pe = (d & 1) ? cosf(ang) : sinf(ang);
    float hv = wemb[(long)wid * DD + d] + pe;
    hf[idx] = hv;
    hb[idx] = f2b(hv);
}

// ---------------- bf16 MFMA GEMM with optional split-K over blockIdx.z ----------------
// C[M,N] = A[M,K] @ Bt[N,K]^T (+ bias on z==0). Slice z covers k in [z*Ksl, (z+1)*Ksl).
// fp32 output goes to outf + z*M*N (partials summed later). 128x128 tile, BK=32.
__global__ __launch_bounds__(256) void gemm_bf16(
    const ushort_t* __restrict__ A, const ushort_t* __restrict__ Bt,
    const float* __restrict__ bias,
    ushort_t* __restrict__ outb, float* __restrict__ outf,
    int M, int N, int K, int Ksl, int relu)
{
    __shared__ __align__(16) ushort_t As[128 * 32];
    __shared__ __align__(16) ushort_t Bs[128 * 32];
    const int tid = threadIdx.x;
    const int wave = tid >> 6, lane = tid & 63;
    const int quad = lane >> 4, l16 = lane & 15;
    const int m0 = blockIdx.y * 128, n0 = blockIdx.x * 128;
    const int z = blockIdx.z;
    const int kbase = z * Ksl;
    const int wm = (wave >> 1) * 64, wn = (wave & 1) * 64;
    const ushort_t* Ab = A + (long)m0 * K;
    const ushort_t* Bb = Bt + (long)n0 * K;

    f32x4 acc[4][4];
#pragma unroll
    for (int mi = 0; mi < 4; ++mi)
#pragma unroll
        for (int ni = 0; ni < 4; ++ni) acc[mi][ni] = (f32x4){0.f, 0.f, 0.f, 0.f};

    const int nk = Ksl >> 5;
    for (int kt = 0; kt < nk; ++kt) {
        const int k0 = kbase + (kt << 5);
        __syncthreads();
#pragma unroll
        for (int i = 0; i < 2; ++i) {
            int c = tid + i * 256;
            int row = c >> 2, kc = (c & 3) * 8;
            char* la = (char*)As + (wave * 1024 + i * 4096);
            char* lb = (char*)Bs + (wave * 1024 + i * 4096);
            gl2lds16(&Ab[(long)row * K + k0 + kc], la);
            gl2lds16(&Bb[(long)row * K + k0 + kc], lb);
        }
        __syncthreads();
        bf16x8 af[4], bfr[4];
#pragma unroll
        for (int t = 0; t < 4; ++t)
            af[t] = *(const bf16x8*)&As[(wm + t * 16 + l16) * 32 + quad * 8];
#pragma unroll
        for (int t = 0; t < 4; ++t)
            bfr[t] = *(const bf16x8*)&Bs[(wn + t * 16 + l16) * 32 + quad * 8];
#pragma unroll
        for (int mi = 0; mi < 4; ++mi)
#pragma unroll
            for (int ni = 0; ni < 4; ++ni)
                acc[mi][ni] = __builtin_amdgcn_mfma_f32_16x16x32_bf16(
                    af[mi], bfr[ni], acc[mi][ni], 0, 0, 0);
    }

    float* outfz = outf ? outf + (size_t)z * M * N : nullptr;
#pragma unroll
    for (int ni = 0; ni < 4; ++ni) {
        int col = n0 + wn + ni * 16 + l16;
        float bv = (bias && z == 0) ? bias[col] : 0.f;
#pragma unroll
        for (int mi = 0; mi < 4; ++mi) {
#pragma unroll
            for (int r = 0; r < 4; ++r) {
                int row = m0 + wm + mi * 16 + quad * 4 + r;
                float vv = acc[mi][ni][r] + bv;
                if (relu) vv = fmaxf(vv, 0.f);
                if (outb) outb[(long)row * N + col] = f2b(vv);
                if (outfz) outfz[(long)row * N + col] = vv;
            }
        }
    }
}

// ---------------- MFMA attention (fused qkv input, stride 2304) ----------------
#define QS_STR 72
#define VT_STR 264
#define P_STR  264
#define S_STR  257
#define PE_STR 53

__global__ __launch_bounds__(256) void attn_kernel(
    const ushort_t* __restrict__ qkv,
    const int* __restrict__ adjm, const int* __restrict__ etyp,
    const float* __restrict__ eemb, ushort_t* __restrict__ out)
{
    __shared__ __align__(16) char smem[64448];
    ushort_t* VT = (ushort_t*)smem;                         // 64 x 264 bf16
    float*    S  = (float*)(smem + 33792);                  // 16 x 257 f32
    ushort_t* P  = (ushort_t*)(smem + 50240);               // 16 x 264 bf16
    float*    Pe = (float*)(smem + 58688);                  // 16 x 53 f32
    char*     U  = smem + 62080;                            // union: Qs / red
    float* invrow = (float*)(smem + 64384);                 // 16 f32
    ushort_t* Qs = (ushort_t*)U;                            // 16 x 72 bf16
    float*    red = (float*)U;                              // [2][16][17]

    const int blk = blockIdx.x;
    const int qt = blk & 15;
    const int h  = (blk >> 4) % HH;
    const int b  = blk / (16 * HH);
    const int i0 = qt * 16;
    const int tid = threadIdx.x;
    const int wave = tid >> 6, lane = tid & 63;
    const int quad = lane >> 4, l16 = lane & 15;

    // ---- stage Qs (16x64) and VT (64x256, transposed) ----
    if (tid < 128) {
        int row = tid >> 3, d0 = (tid & 7) * 8;
        *(int4*)&Qs[row * QS_STR + d0] =
            *(const int4*)&qkv[((long)(b * LL + i0 + row)) * QKVS + h * HDD + d0];
    }
#pragma unroll
    for (int i = 0; i < 8; ++i) {
        int c = tid + i * 256;           // 2048 chunks
        int j = c >> 3, d0 = (c & 7) * 8;
        int4 raw = *(const int4*)&qkv[((long)(b * LL + j)) * QKVS + 2 * DD + h * HDD + d0];
        const ushort_t* vals = (const ushort_t*)&raw;
#pragma unroll
        for (int u = 0; u < 8; ++u) VT[(d0 + u) * VT_STR + j] = vals[u];
    }
    __syncthreads();

    // ---- phase 1: Pe = Q @ E^T ----
    {
        int e = wave * 16 + l16;
        f32x4 acc = (f32x4){0.f, 0.f, 0.f, 0.f};
#pragma unroll
        for (int kk = 0; kk < 2; ++kk) {
            bf16x8 af = *(const bf16x8*)&Qs[l16 * QS_STR + kk * 32 + quad * 8];
            bf16x8 bf = (bf16x8){0, 0, 0, 0, 0, 0, 0, 0};
            if (e < EE) {
                const float* ep = &eemb[(long)e * HDD + kk * 32 + quad * 8];
#pragma unroll
                for (int u = 0; u < 8; ++u) bf[u] = (__bf16)ep[u];
            }
            acc = __builtin_amdgcn_mfma_f32_16x16x32_bf16(af, bf, acc, 0, 0, 0);
        }
        if (e < EE) {
#pragma unroll
            for (int r = 0; r < 4; ++r) Pe[(quad * 4 + r) * PE_STR + e] = acc[r];
        }
    }

    // ---- phase 2: S = Q @ K^T (K B-frags straight from global, L2-hot) ----
#pragma unroll
    for (int jt = 0; jt < 4; ++jt) {
        int jtile = wave * 4 + jt;
        int j = jtile * 16 + l16;
        f32x4 acc = (f32x4){0.f, 0.f, 0.f, 0.f};
#pragma unroll
        for (int kk = 0; kk < 2; ++kk) {
            bf16x8 af = *(const bf16x8*)&Qs[l16 * QS_STR + kk * 32 + quad * 8];
            bf16x8 bf = *(const bf16x8*)&qkv[((long)(b * LL + j)) * QKVS + DD + h * HDD + kk * 32 + quad * 8];
            acc = __builtin_amdgcn_mfma_f32_16x16x32_bf16(af, bf, acc, 0, 0, 0);
        }
#pragma unroll
        for (int r = 0; r < 4; ++r)
            S[(quad * 4 + r) * S_STR + jtile * 16 + l16] = acc[r];
    }
    __syncthreads();

    // ---- phase 3: masked softmax with edge gather ----
    {
        const int row = tid & 15, seg = tid >> 4;
        const int i = i0 + row;
        const int* etp = etyp + ((long)(b * LL + i)) * LL + seg * 16;
        const int* adp = adjm + ((long)(b * LL + i)) * LL + seg * 16;
        int etv[16], adv[16];
#pragma unroll
        for (int t = 0; t < 4; ++t) {
            *(int4*)&etv[t * 4] = *(const int4*)&etp[t * 4];
            *(int4*)&adv[t * 4] = *(const int4*)&adp[t * 4];
        }
        float vals[16];
        float pmax = -1e30f;
#pragma unroll
        for (int c = 0; c < 16; ++c) {
            float s = S[row * S_STR + seg * 16 + c];
            float pe = Pe[row * PE_STR + etv[c]];
            float vv = adv[c] ? (s + pe) * 0.125f : -1e30f;
            vals[c] = vv;
            pmax = fmaxf(pmax, vv);
        }
        red[row * 17 + seg] = pmax;
        __syncthreads();
        float m = -1e30f;
#pragma unroll
        for (int g = 0; g < 16; ++g) m = fmaxf(m, red[row * 17 + g]);
        float sum = 0.f;
#pragma unroll
        for (int c = 0; c < 16; ++c) {
            float p = __expf(vals[c] - m);
            ushort_t pb = f2b(p);
            sum += b2f(pb);
            P[row * P_STR + seg * 16 + c] = pb;
        }
        red[272 + row * 17 + seg] = sum;
        __syncthreads();
        if (tid < 16) {
            float tot = 0.f;
#pragma unroll
            for (int g = 0; g < 16; ++g) tot += red[272 + tid * 17 + g];
            invrow[tid] = 1.f / tot;
        }
        __syncthreads();
    }

    // ---- phase 4: O = P @ V ----
    {
        f32x4 acc = (f32x4){0.f, 0.f, 0.f, 0.f};
#pragma unroll
        for (int kt = 0; kt < 8; ++kt) {
            bf16x8 af = *(const bf16x8*)&P[l16 * P_STR + kt * 32 + quad * 8];
            bf16x8 bf = *(const bf16x8*)&VT[(wave * 16 + l16) * VT_STR + kt * 32 + quad * 8];
            acc = __builtin_amdgcn_mfma_f32_16x16x32_bf16(af, bf, acc, 0, 0, 0);
        }
#pragma unroll
        for (int r = 0; r < 4; ++r) {
            int row = quad * 4 + r;
            float ov = acc[r] * invrow[row];
            out[((long)(b * LL + i0 + row)) * DD + h * HDD + wave * 16 + l16] = f2b(ov);
        }
    }
}

// ---------------- residual + layernorm; sums nparts split-K partials ----------------
__global__ __launch_bounds__(256) void ln_kernel(
    float* __restrict__ hf, ushort_t* __restrict__ hb,
    const float* __restrict__ proj, int nparts,
    const float* __restrict__ g, const float* __restrict__ be)
{
    const int r = blockIdx.x, tid = threadIdx.x;
    const long rb = (long)r * DD;
    float x[3];
#pragma unroll
    for (int i = 0; i < 3; ++i) {
        int d = tid + i * 256;
        float t = hf[rb + d];
        for (int p = 0; p < nparts; ++p) t += proj[(size_t)p * TOKD + rb + d];
        x[i] = t;
    }
    float s = x[0] + x[1] + x[2];
    float s2 = x[0] * x[0] + x[1] * x[1] + x[2] * x[2];
#pragma unroll
    for (int o = 1; o < 64; o <<= 1) { s += __shfl_xor(s, o); s2 += __shfl_xor(s2, o); }
    __shared__ float rs[4], rq[4];
    int wave = tid >> 6;
    if ((tid & 63) == 0) { rs[wave] = s; rq[wave] = s2; }
    __syncthreads();
    float S  = rs[0] + rs[1] + rs[2] + rs[3];
    float S2 = rq[0] + rq[1] + rq[2] + rq[3];
    float mean = S * (1.f / (float)DD);
    float var  = S2 * (1.f / (float)DD) - mean * mean;
    float rstd = rsqrtf(var + 1e-5f);
#pragma unroll
    for (int i = 0; i < 3; ++i) {
        int d = tid + i * 256;
        float y = (x[i] - mean) * rstd * g[d] + be[d];
        hf[rb + d] = y;
        hb[rb + d] = f2b(y);
    }
}

// ---------------- classifier head ----------------
__global__ __launch_bounds__(256) void cls_kernel(
    const float* __restrict__ hf, const float* __restrict__ W,
    const float* __restrict__ bias, float* __restrict__ out)
{
    int b = blockIdx.x, tid = threadIdx.x;
    const float* hr = hf + (long)b * LL * DD;
    float p0 = 0.f, p1 = 0.f;
    for (int d = tid; d < DD; d += 256) {
        float hv = hr[d];
        p0 = fmaf(hv, W[d * 2 + 0], p0);
        p1 = fmaf(hv, W[d * 2 + 1], p1);
    }
#pragma unroll
    for (int o = 1; o < 64; o <<= 1) { p0 += __shfl_xor(p0, o); p1 += __shfl_xor(p1, o); }
    __shared__ float r0[4], r1[4];
    int wave = tid >> 6;
    if ((tid & 63) == 0) { r0[wave] = p0; r1[wave] = p1; }
    __syncthreads();
    if (tid == 0) {
        out[b * 2 + 0] = r0[0] + r0[1] + r0[2] + r0[3] + bias[0];
        out[b * 2 + 1] = r1[0] + r1[1] + r1[2] + r1[3] + bias[1];
    }
}

extern "C" void kernel_launch(void* const* d_in, const int* in_sizes, int n_in,
                              void* d_out, int out_size, void* d_ws, size_t ws_size,
                              hipStream_t stream)
{
    const int* word_ids = (const int*)d_in[0];
    const int* adjm     = (const int*)d_in[1];
    const int* etyp     = (const int*)d_in[2];
    const float* wemb   = (const float*)d_in[3];
    const float* eemb   = (const float*)d_in[4];
    const float* Wq     = (const float*)d_in[5];
    const float* bq     = (const float*)d_in[6];
    const float* Wk     = (const float*)d_in[7];
    const float* bk     = (const float*)d_in[8];
    const float* Wv     = (const float*)d_in[9];
    const float* bv     = (const float*)d_in[10];
    const float* Wo     = (const float*)d_in[11];
    const float* bo     = (const float*)d_in[12];
    const float* ln1g   = (const float*)d_in[13];
    const float* ln1b   = (const float*)d_in[14];
    const float* W1     = (const float*)d_in[15];
    const float* b1     = (const float*)d_in[16];
    const float* W2     = (const float*)d_in[17];
    const float* b2     = (const float*)d_in[18];
    const float* ln2g   = (const float*)d_in[19];
    const float* ln2b   = (const float*)d_in[20];
    const float* clsW   = (const float*)d_in[21];
    const float* clsb   = (const float*)d_in[22];
    float* outp = (float*)d_out;

    char* ws = (char*)d_ws;
    size_t off = 0;
    auto alloc = [&](size_t bytes) -> char* {
        char* p = ws + off;
        off += (bytes + 255) & ~(size_t)255;
        return p;
    };
    const size_t DxD = (size_t)DD * DD;
    const size_t DxF = (size_t)DD * FF;
    const size_t TOK = (size_t)BB * LL;
    const size_t LSTR = (size_t)QKVS * DD + DxD + 2 * DxF;  // cached bf16 elems / layer = 7,077,888

    // ---- proven-safe base (61.34 MB, same as round-2's passing layout) ----
    float*    hf  = (float*)alloc(TOK * DD * 4);        // 12.58 MB
    ushort_t* hb  = (ushort_t*)alloc(TOK * DD * 2);     //  6.29 MB
    ushort_t* qkv = (ushort_t*)alloc(TOK * QKVS * 2);   // 18.87 MB  (q|k|v fused)
    ushort_t* ao  = (ushort_t*)alloc(TOK * DD * 2);     //  6.29 MB
    float*    pjf = (float*)alloc(TOK * DD * 4);        // 12.58 MB  (partial 0)
    ushort_t* tw  = (ushort_t*)alloc(DxF * 2);          //  4.72 MB  JIT transpose slot
    ushort_t* ff1 = qkv;  // aliases qkv+ao span (exactly 25.17 MB), dead by FFN time
    // ---- tiers by ws_size ----
    size_t tier1 = off + TOK * DD * 4;                  // +1 partial
    size_t tier2 = tier1 + 2 * TOK * DD * 4;            // +3 partials total
    size_t tier3 = tier2 + NLL * LSTR * 2;              // + full transposed-weight cache
    int S_o = 1, S_f = 1;
    ushort_t* cache = nullptr;
    if (ws_size >= tier1) { (void)alloc(TOK * DD * 4); S_o = 2; S_f = 2; }
    if (ws_size >= tier2) { (void)alloc(2 * TOK * DD * 4); S_f = 4; }
    if (ws_size >= tier3) { cache = (ushort_t*)alloc(NLL * LSTR * 2); }
    (void)in_sizes; (void)n_in; (void)out_size;

    dim3 tb(32, 8, 1);
    if (cache) {  // pre-transpose ALL weights, batched over layers (grid.z = 4)
        transpose_f2b<<<dim3(24, 24, NLL), tb, 0, stream>>>(Wq, cache,                 DD, DD, DxD, LSTR);
        transpose_f2b<<<dim3(24, 24, NLL), tb, 0, stream>>>(Wk, cache + DD * DD,       DD, DD, DxD, LSTR);
        transpose_f2b<<<dim3(24, 24, NLL), tb, 0, stream>>>(Wv, cache + 2 * DD * DD,   DD, DD, DxD, LSTR);
        transpose_f2b<<<dim3(24, 24, NLL), tb, 0, stream>>>(Wo, cache + 3 * DD * DD,   DD, DD, DxD, LSTR);
        transpose_f2b<<<dim3(96, 24, NLL), tb, 0, stream>>>(W1, cache + 4 * DD * DD,   DD, FF, DxF, LSTR);
        transpose_f2b<<<dim3(24, 96, NLL), tb, 0, stream>>>(W2, cache + 4 * DD * DD + DxF, FF, DD, DxF, LSTR);
    }

    embed_kernel<<<(int)(TOK * DD / 256), 256, 0, stream>>>(word_ids, wemb, hf, hb);

    const int M = (int)TOK; // 4096
    for (int l = 0; l < NLL; ++l) {
        const ushort_t *BtQKV, *BtO, *BtW1, *BtW2;
        if (cache) {
            const ushort_t* base = cache + (size_t)l * LSTR;
            BtQKV = base; BtO = base + 3 * DD * DD;
            BtW1 = base + 4 * DD * DD; BtW2 = base + 4 * DD * DD + DxF;
        } else {
            BtQKV = tw; BtO = tw; BtW1 = tw; BtW2 = tw;
        }
        // fused QKV bias into (dead-at-this-point) pjf
        fuse_bias_kernel<<<9, 256, 0, stream>>>(bq, bk, bv, l, pjf);
        if (!cache) {
            transpose_f2b<<<dim3(24, 24), tb, 0, stream>>>(Wq + (size_t)l * DxD, tw,               DD, DD, 0, 0);
            transpose_f2b<<<dim3(24, 24), tb, 0, stream>>>(Wk + (size_t)l * DxD, tw + DD * DD,     DD, DD, 0, 0);
            transpose_f2b<<<dim3(24, 24), tb, 0, stream>>>(Wv + (size_t)l * DxD, tw + 2 * DD * DD, DD, DD, 0, 0);
        }
        gemm_bf16<<<dim3(QKVS / 128, M / 128, 1), 256, 0, stream>>>(
            hb, BtQKV, pjf, qkv, nullptr, M, QKVS, DD, DD, 0);
        attn_kernel<<<BB * HH * 16, 256, 0, stream>>>(qkv, adjm, etyp, eemb, ao);
        if (!cache)
            transpose_f2b<<<dim3(24, 24), tb, 0, stream>>>(Wo + (size_t)l * DxD, tw, DD, DD, 0, 0);
        gemm_bf16<<<dim3(DD / 128, M / 128, S_o), 256, 0, stream>>>(
            ao, BtO, bo + l * DD, nullptr, pjf, M, DD, DD, DD / S_o, 0);
        ln_kernel<<<M, 256, 0, stream>>>(hf, hb, pjf, S_o, ln1g + l * DD, ln1b + l * DD);
        if (!cache)
            transpose_f2b<<<dim3(96, 24), tb, 0, stream>>>(W1 + (size_t)l * DxF, tw, DD, FF, 0, 0);
        gemm_bf16<<<dim3(FF / 128, M / 128, 1), 256, 0, stream>>>(
            hb, BtW1, b1 + l * FF, ff1, nullptr, M, FF, DD, DD, 1);
        if (!cache)
            transpose_f2b<<<dim3(24, 96), tb, 0, stream>>>(W2 + (size_t)l * DxF, tw, FF, DD, 0, 0);
        gemm_bf16<<<dim3(DD / 128, M / 128, S_f), 256, 0, stream>>>(
            ff1, BtW2, b2 + l * DD, nullptr, pjf, M, DD, FF, FF / S_f, 0);
        ln_kernel<<<M, 256, 0, stream>>>(hf, hb, pjf, S_f, ln2g + l * DD, ln2b + l * DD);
    }
    cls_kernel<<<BB, 256, 0, stream>>>(hf, clsW, clsb, outp);
}